// Round 7
// baseline (300.293 us; speedup 1.0000x reference)
//
#include <hip/hip_runtime.h>

typedef _Float16 f16;
typedef _Float16 f16x4 __attribute__((ext_vector_type(4)));
typedef _Float16 f16x8 __attribute__((ext_vector_type(8)));
typedef float f32x4 __attribute__((ext_vector_type(4)));
typedef float f32x16 __attribute__((ext_vector_type(16)));
typedef unsigned u32x4 __attribute__((ext_vector_type(4)));

#define DEVINL __device__ __forceinline__
#define VMCNT(n) asm volatile("s_waitcnt vmcnt(" #n ")" ::: "memory")
#define SCHEDBAR() __builtin_amdgcn_sched_barrier(0)

// async global->LDS, 16B per lane. LDS dest must be uniform-base + lane*16.
DEVINL void gload16(const void* g, void* l) {
    __builtin_amdgcn_global_load_lds(
        (const __attribute__((address_space(1))) unsigned int*)g,
        (__attribute__((address_space(3))) unsigned int*)l, 16, 0, 0);
}

DEVINL unsigned pk2(float a, float b) {
    auto v = __builtin_amdgcn_cvt_pkrtz(a, b);  // v_cvt_pkrtz_f16_f32
    return __builtin_bit_cast(unsigned, v);
}

// ---------------------------------------------------------------- convert
__global__ __launch_bounds__(256) void cvt_kernel(const float* __restrict__ in,
                                                  f16* __restrict__ out, int n4) {
    int i = blockIdx.x * 256 + threadIdx.x;
    int st = gridDim.x * 256;
    for (; i < n4; i += st) {
        float4 v = reinterpret_cast<const float4*>(in)[i];
        f16x4 o = {(f16)v.x, (f16)v.y, (f16)v.z, (f16)v.w};
        reinterpret_cast<f16x4*>(out)[i] = o;
    }
}

// ---------------------------------------------------------------- in_proj GEMM (proven 2-phase, + XCD chunk)
// C[8192,3072] = A * B^T + bias; scatter Q (prescaled by 0.125*log2e), K, Vt.
__global__ __launch_bounds__(256) void gemm_in(const f16* __restrict__ A,
                                               const f16* __restrict__ Bm,
                                               const float* __restrict__ bias,
                                               f16* __restrict__ Qw, f16* __restrict__ Kw,
                                               f16* __restrict__ Vtw) {
    constexpr int K = 1024, NT = K / 32;
    __shared__ f16 As[2][128 * 32];
    __shared__ f16 Bs[2][128 * 32];
    const int t = threadIdx.x;
    const int wave = t >> 6, lane = t & 63, lr = lane & 15, lg = lane >> 4;
    const int wr = wave >> 1, wc = wave & 1;
    const int wg = blockIdx.x;
    const int swz = (wg & 7) * 192 + (wg >> 3);  // 1536 % 8 == 0 -> bijective
    const int m0 = (swz / 24) * 128, n0 = (swz % 24) * 128;

    const f16* Ag = A + (m0 + (t >> 2)) * K + (t & 3) * 8;
    const f16* Bg = Bm + (n0 + (t >> 2)) * K + (t & 3) * 8;

    f32x4 acc[4][4] = {};

    auto stage = [&](int buf, int kt) {
        const f16* a = Ag + kt * 32;
        const f16* b = Bg + kt * 32;
        f16* al = &As[buf][t * 8];
        f16* bl = &Bs[buf][t * 8];
        gload16(a, al);
        gload16(a + 64 * K, al + 64 * 32);
        gload16(b, bl);
        gload16(b + 64 * K, bl + 64 * 32);
    };

    stage(0, 0);
    __syncthreads();
    int cur = 0;
    for (int kt = 0; kt < NT; ++kt) {
        if (kt + 1 < NT) stage(cur ^ 1, kt + 1);
        const f16* as = &As[cur][0];
        const f16* bs = &Bs[cur][0];
        f16x8 af[4], bf[4];
#pragma unroll
        for (int i = 0; i < 4; ++i)
            af[i] = *(const f16x8*)&as[(wr * 64 + i * 16 + lr) * 32 + lg * 8];
#pragma unroll
        for (int i = 0; i < 4; ++i)
            bf[i] = *(const f16x8*)&bs[(wc * 64 + i * 16 + lr) * 32 + lg * 8];
#pragma unroll
        for (int i = 0; i < 4; ++i)
#pragma unroll
            for (int j = 0; j < 4; ++j)
                acc[i][j] = __builtin_amdgcn_mfma_f32_16x16x32_f16(af[i], bf[j], acc[i][j], 0, 0, 0);
        __syncthreads();
        cur ^= 1;
    }

    const float SCQ = 0.18033688011112042f;  // (1/sqrt(64)) * log2(e)
#pragma unroll
    for (int nf = 0; nf < 4; ++nf) {
        int n = n0 + wc * 64 + nf * 16 + lr;
        float bv = bias[n];
        int part = n >> 10, e = n & 1023, hh = e >> 6, dd = e & 63;
#pragma unroll
        for (int mf = 0; mf < 4; ++mf) {
            int m = m0 + wr * 64 + mf * 16 + lg * 4;
            int bb = m >> 10, ss = m & 1023;
            if (part == 0) {
                f16* dst = Qw + ((bb * 16 + hh) * 1024 + ss) * 64 + dd;
#pragma unroll
                for (int r = 0; r < 4; ++r) dst[r * 64] = (f16)((acc[mf][nf][r] + bv) * SCQ);
            } else if (part == 1) {
                f16* dst = Kw + ((bb * 16 + hh) * 1024 + ss) * 64 + dd;
#pragma unroll
                for (int r = 0; r < 4; ++r) dst[r * 64] = (f16)(acc[mf][nf][r] + bv);
            } else {
                f16x4 pkv;
#pragma unroll
                for (int r = 0; r < 4; ++r) pkv[r] = (f16)(acc[mf][nf][r] + bv);
                *(f16x4*)(Vtw + ((bb * 16 + hh) * 64 + dd) * 1024 + ss) = pkv;
            }
        }
    }
}

// ---------------------------------------------------------------- out_proj GEMM (proven 2-phase, + XCD chunk)
__global__ __launch_bounds__(256) void gemm_out(const f16* __restrict__ A,
                                                const f16* __restrict__ Bm,
                                                const float* __restrict__ bias,
                                                float* __restrict__ Cout) {
    constexpr int K = 1024, NT = K / 32;
    __shared__ f16 As[2][128 * 32];
    __shared__ f16 Bs[2][128 * 32];
    const int t = threadIdx.x;
    const int wave = t >> 6, lane = t & 63, lr = lane & 15, lg = lane >> 4;
    const int wr = wave >> 1, wc = wave & 1;
    const int wg = blockIdx.x;
    const int swz = (wg & 7) * 64 + (wg >> 3);  // 512 % 8 == 0 -> bijective
    const int m0 = (swz / 8) * 128, n0 = (swz % 8) * 128;

    const f16* Ag = A + (m0 + (t >> 2)) * K + (t & 3) * 8;
    const f16* Bg = Bm + (n0 + (t >> 2)) * K + (t & 3) * 8;

    f32x4 acc[4][4] = {};

    auto stage = [&](int buf, int kt) {
        const f16* a = Ag + kt * 32;
        const f16* b = Bg + kt * 32;
        f16* al = &As[buf][t * 8];
        f16* bl = &Bs[buf][t * 8];
        gload16(a, al);
        gload16(a + 64 * K, al + 64 * 32);
        gload16(b, bl);
        gload16(b + 64 * K, bl + 64 * 32);
    };

    stage(0, 0);
    __syncthreads();
    int cur = 0;
    for (int kt = 0; kt < NT; ++kt) {
        if (kt + 1 < NT) stage(cur ^ 1, kt + 1);
        const f16* as = &As[cur][0];
        const f16* bs = &Bs[cur][0];
        f16x8 af[4], bf[4];
#pragma unroll
        for (int i = 0; i < 4; ++i)
            af[i] = *(const f16x8*)&as[(wr * 64 + i * 16 + lr) * 32 + lg * 8];
#pragma unroll
        for (int i = 0; i < 4; ++i)
            bf[i] = *(const f16x8*)&bs[(wc * 64 + i * 16 + lr) * 32 + lg * 8];
#pragma unroll
        for (int i = 0; i < 4; ++i)
#pragma unroll
            for (int j = 0; j < 4; ++j)
                acc[i][j] = __builtin_amdgcn_mfma_f32_16x16x32_f16(af[i], bf[j], acc[i][j], 0, 0, 0);
        __syncthreads();
        cur ^= 1;
    }
#pragma unroll
    for (int nf = 0; nf < 4; ++nf) {
        int n = n0 + wc * 64 + nf * 16 + lr;
        float bv = bias[n];
#pragma unroll
        for (int mf = 0; mf < 4; ++mf) {
            int m = m0 + wr * 64 + mf * 16 + lg * 4;
#pragma unroll
            for (int r = 0; r < 4; ++r) Cout[(m + r) * 1024 + n] = acc[mf][nf][r] + bv;
        }
    }
}

// ---------------------------------------------------------------- flash attention (4 waves, ring-4, XCD=batch)
// 1024 WGs x 256 thr = 4 waves x 32 q-rows (128 q/block). Ring-4 K/V slots
// (64 KB LDS), prefetch depth 3, counted VMCNT(8/4/0) — the round-3
// replay-validated skeleton. sched_barrier(0) pins stop the compiler moving
// stage-loads or epilogue stores across wave barriers (round-6 race fix:
// ring-2 made the epilogue region overlap the final iteration's K slot).
// XCD-chunk: gid=(wg&7)*128+(wg>>3) => each XCD owns one batch b (4MB K/V = L2).
// Q prescaled by 0.125*log2e in gemm_in.
__global__ __launch_bounds__(256) void attn_kernel(const f16* __restrict__ Qw,
                                                   const f16* __restrict__ Kw,
                                                   const f16* __restrict__ Vtw,
                                                   f16* __restrict__ AO) {
    __shared__ char LDSb[65536];  // K slots: [0,32768) 4x8KB ; V slots: [32768,65536)
    const int t = threadIdx.x, wave = t >> 6, lane = t & 63;
    const int ql = lane & 31, hi = lane >> 5;
    const int wg = blockIdx.x;
    const int gid = (wg & 7) * 128 + (wg >> 3);
    const int qt = gid & 7, h = (gid >> 3) & 15, b = gid >> 7;
    const f16* Qp = Qw + (b * 16 + h) * 1024 * 64;
    const f16* Kp = Kw + (b * 16 + h) * 1024 * 64;
    const f16* Vp = Vtw + (b * 16 + h) * 64 * 1024;
    const int q0 = qt * 128 + wave * 32;

    // Q as B-operand (prescaled): qb[s] = Q[q0+ql][s*16 + hi*8 + j]
    f16x8 qb[4];
#pragma unroll
    for (int s = 0; s < 4; ++s)
        qb[s] = *(const f16x8*)&Qp[(q0 + ql) * 64 + s * 16 + hi * 8];

    // staging: 256 thr x 2 rows each for K and V tiles (64 rows x 128B = 8KB each)
    const int srow0 = t >> 3;
    const int sw = (t & 7) << 4;
    auto stage_kv = [&](int slot, int kv) {  // kv = tile*64
#pragma unroll
        for (int c = 0; c < 2; ++c) {
            int row = c * 32 + srow0;
            int gwb = sw ^ ((row & 7) << 4);  // pre-swizzle SOURCE (rule 21)
            gload16((const char*)(Kp + (kv + row) * 64) + gwb,
                    LDSb + slot * 8192 + c * 4096 + t * 16);
            gload16((const char*)(Vp + row * 1024 + kv) + gwb,
                    LDSb + 32768 + slot * 8192 + c * 4096 + t * 16);
        }
    };

    f32x16 o0 = 0.f, o1 = 0.f;
    float mraw = -1e30f, lsum = 0.f;

    stage_kv(0, 0);
    stage_kv(1, 64);
    stage_kv(2, 128);
    VMCNT(8);  // own slice of slot 0 landed (12 issued, oldest 4 done)

    for (int kv = 0; kv < 16; ++kv) {
        __builtin_amdgcn_s_barrier();
        SCHEDBAR();  // pin: no stage-load may be scheduled above the barrier
        if (kv + 3 < 16) stage_kv((kv + 3) & 3, (kv + 3) * 64);
        const char* Kb = LDSb + (kv & 3) * 8192;
        const char* Vb = LDSb + 32768 + (kv & 3) * 8192;

        // ---- QK^T (swapped): st0 = S^T[kk 0..31][q], st1 = S^T[kk 32..63][q]
        f32x16 st0, st1;
        __builtin_amdgcn_s_setprio(1);
#pragma unroll
        for (int s = 0; s < 4; ++s) {
            int byt = (s * 32 + hi * 16) ^ ((ql & 7) << 4);
            f16x8 k0 = *(const f16x8*)(Kb + ql * 128 + byt);
            f16x8 k1 = *(const f16x8*)(Kb + (32 + ql) * 128 + byt);
            if (s == 0) {
                st0 = __builtin_amdgcn_mfma_f32_32x32x16_f16(k0, qb[0], (f32x16)0.f, 0, 0, 0);
                st1 = __builtin_amdgcn_mfma_f32_32x32x16_f16(k1, qb[0], (f32x16)0.f, 0, 0, 0);
            } else {
                st0 = __builtin_amdgcn_mfma_f32_32x32x16_f16(k0, qb[s], st0, 0, 0, 0);
                st1 = __builtin_amdgcn_mfma_f32_32x32x16_f16(k1, qb[s], st1, 0, 0, 0);
            }
        }
        __builtin_amdgcn_s_setprio(0);

        // ---- lane-local online softmax, tree reductions, defer-max (THR=8 log2)
        float a[16];
#pragma unroll
        for (int r = 0; r < 16; ++r) a[r] = fmaxf(st0[r], st1[r]);
#pragma unroll
        for (int s = 8; s >= 1; s >>= 1)
#pragma unroll
            for (int r = 0; r < 16; ++r)
                if (r < s) a[r] = fmaxf(a[r], a[r + s]);
        float mx = fmaxf(a[0], __shfl_xor(a[0], 32, 64));

        if (__all(mx <= mraw + 8.f)) {
#pragma unroll
            for (int r = 0; r < 16; ++r) st0[r] = exp2f(st0[r] - mraw);
#pragma unroll
            for (int r = 0; r < 16; ++r) st1[r] = exp2f(st1[r] - mraw);
            float sa[16];
#pragma unroll
            for (int r = 0; r < 16; ++r) sa[r] = st0[r] + st1[r];
#pragma unroll
            for (int s = 8; s >= 1; s >>= 1)
#pragma unroll
                for (int r = 0; r < 16; ++r)
                    if (r < s) sa[r] += sa[r + s];
            lsum += sa[0] + __shfl_xor(sa[0], 32, 64);
        } else {
            float mn = fmaxf(mraw, mx);
            float al = exp2f(mraw - mn);
            mraw = mn;
#pragma unroll
            for (int r = 0; r < 16; ++r) st0[r] = exp2f(st0[r] - mn);
#pragma unroll
            for (int r = 0; r < 16; ++r) st1[r] = exp2f(st1[r] - mn);
            float sa[16];
#pragma unroll
            for (int r = 0; r < 16; ++r) sa[r] = st0[r] + st1[r];
#pragma unroll
            for (int s = 8; s >= 1; s >>= 1)
#pragma unroll
                for (int r = 0; r < 16; ++r)
                    if (r < s) sa[r] += sa[r + s];
            lsum = lsum * al + sa[0] + __shfl_xor(sa[0], 32, 64);
            o0 *= al;
            o1 *= al;
        }

        // ---- PV (swapped): O^T[d][q] += V^T[d][kk] P^T[kk][q]
#pragma unroll
        for (int s = 0; s < 4; ++s) {
            const int s1 = s & 1;
            float p0, p1, p2, p3, p4, p5, p6, p7;
            if (s < 2) {
                p0 = st0[8 * s1 + 0]; p1 = st0[8 * s1 + 1]; p2 = st0[8 * s1 + 2]; p3 = st0[8 * s1 + 3];
                p4 = st0[8 * s1 + 4]; p5 = st0[8 * s1 + 5]; p6 = st0[8 * s1 + 6]; p7 = st0[8 * s1 + 7];
            } else {
                p0 = st1[8 * s1 + 0]; p1 = st1[8 * s1 + 1]; p2 = st1[8 * s1 + 2]; p3 = st1[8 * s1 + 3];
                p4 = st1[8 * s1 + 4]; p5 = st1[8 * s1 + 5]; p6 = st1[8 * s1 + 6]; p7 = st1[8 * s1 + 7];
            }
            unsigned c0 = pk2(p0, p1), c1 = pk2(p2, p3);
            unsigned c2 = pk2(p4, p5), c3 = pk2(p6, p7);
            unsigned y0 = __shfl_xor(hi ? c0 : c2, 32, 64);
            unsigned y1 = __shfl_xor(hi ? c1 : c3, 32, 64);
            unsigned w0 = hi ? y0 : c0;
            unsigned w1 = hi ? y1 : c1;
            unsigned w2 = hi ? c2 : y0;
            unsigned w3 = hi ? c3 : y1;
            u32x4 pw = {w0, w1, w2, w3};
            f16x8 pf = __builtin_bit_cast(f16x8, pw);
            __builtin_amdgcn_s_setprio(1);
#pragma unroll
            for (int db = 0; db < 2; ++db) {
                int row = db * 32 + ql;
                int byt = (s * 32 + hi * 16) ^ ((row & 7) << 4);
                f16x8 vf = *(const f16x8*)(Vb + row * 128 + byt);
                if (db == 0)
                    o0 = __builtin_amdgcn_mfma_f32_32x32x16_f16(vf, pf, o0, 0, 0, 0);
                else
                    o1 = __builtin_amdgcn_mfma_f32_32x32x16_f16(vf, pf, o1, 0, 0, 0);
            }
            __builtin_amdgcn_s_setprio(0);
        }
        // pre-barrier wait: own slice of kv+1 landed (counted; never drains mid-loop)
        if (kv <= 12) VMCNT(8);
        else if (kv == 13) VMCNT(4);
        else if (kv == 14) VMCNT(0);
        SCHEDBAR();
    }

    // ---- epilogue: O^T -> LDS (swizzled transpose) -> coalesced AO[s][h*64+d]
    // writes K slots 0-1 ([0,16384)); final iteration read slot 3 — disjoint,
    // and slot 1's last reader (kv=13) is two barriers upstream.
    SCHEDBAR();  // pin: no epilogue store above the final loop barrier
    float inv = 1.0f / lsum;
    char* obase = LDSb + wave * 4096;  // 4 waves x 4KB in dead K region
#pragma unroll
    for (int db = 0; db < 2; ++db)
#pragma unroll
        for (int r = 0; r < 16; ++r) {
            int d = db * 32 + (r & 3) + 8 * (r >> 2) + 4 * hi;
            float v = (db == 0 ? o0[r] : o1[r]) * inv;
            *(f16*)(obase + ql * 128 + ((2 * d) ^ ((ql & 7) << 4))) = (f16)v;
        }
    __syncthreads();
    const int rl = lane >> 1, c4 = (lane & 1) * 4;
#pragma unroll
    for (int i = 0; i < 4; ++i) {
        f16x8 ov = *(const f16x8*)(obase + rl * 128 + (((c4 + i) * 16) ^ ((rl & 7) << 4)));
        *(f16x8*)&AO[(b * 1024 + q0 + rl) * 1024 + h * 64 + (c4 + i) * 8] = ov;
    }
}

// ---------------------------------------------------------------- launch
extern "C" void kernel_launch(void* const* d_in, const int* in_sizes, int n_in,
                              void* d_out, int out_size, void* d_ws, size_t ws_size,
                              hipStream_t stream) {
    const float* qkv = (const float*)d_in[0];
    const float* w_in = (const float*)d_in[1];
    const float* b_in = (const float*)d_in[2];
    const float* w_out = (const float*)d_in[3];
    const float* b_out = (const float*)d_in[4];
    float* out = (float*)d_out;

    f16* Xh = (f16*)d_ws;            // 8192*1024
    f16* Wih = Xh + 8388608;         // 3072*1024
    f16* Woh = Wih + 3145728;        // 1024*1024
    f16* Qw = Woh + 1048576;         // [8][16][1024][64]  (prescaled)
    f16* Kw = Qw + 8388608;          // [8][16][1024][64]
    f16* Vtw = Kw + 8388608;         // [8][16][64][1024]
    f16* AO = Xh;

    cvt_kernel<<<2048, 256, 0, stream>>>(qkv, Xh, 8388608 / 4);
    cvt_kernel<<<1024, 256, 0, stream>>>(w_in, Wih, 3145728 / 4);
    cvt_kernel<<<512, 256, 0, stream>>>(w_out, Woh, 1048576 / 4);

    gemm_in<<<1536, 256, 0, stream>>>(Xh, Wih, b_in, Qw, Kw, Vtw);
    attn_kernel<<<1024, 256, 0, stream>>>(Qw, Kw, Vtw, AO);
    gemm_out<<<512, 256, 0, stream>>>(AO, Woh, b_out, out);
}

// Round 9
// 296.668 us; speedup vs baseline: 1.0122x; 1.0122x over previous
//
#include <hip/hip_runtime.h>

typedef _Float16 f16;
typedef _Float16 f16x4 __attribute__((ext_vector_type(4)));
typedef _Float16 f16x8 __attribute__((ext_vector_type(8)));
typedef float f32x4 __attribute__((ext_vector_type(4)));
typedef float f32x16 __attribute__((ext_vector_type(16)));
typedef unsigned u32x4 __attribute__((ext_vector_type(4)));

#define DEVINL __device__ __forceinline__
#define VMCNT(n) asm volatile("s_waitcnt vmcnt(" #n ")" ::: "memory")
#define SCHEDBAR() __builtin_amdgcn_sched_barrier(0)

// async global->LDS, 16B per lane. LDS dest must be uniform-base + lane*16.
DEVINL void gload16(const void* g, void* l) {
    __builtin_amdgcn_global_load_lds(
        (const __attribute__((address_space(1))) unsigned int*)g,
        (__attribute__((address_space(3))) unsigned int*)l, 16, 0, 0);
}

DEVINL unsigned pk2(float a, float b) {
    auto v = __builtin_amdgcn_cvt_pkrtz(a, b);  // v_cvt_pkrtz_f16_f32
    return __builtin_bit_cast(unsigned, v);
}

// ---------------------------------------------------------------- convert
__global__ __launch_bounds__(256) void cvt_kernel(const float* __restrict__ in,
                                                  f16* __restrict__ out, int n4) {
    int i = blockIdx.x * 256 + threadIdx.x;
    int st = gridDim.x * 256;
    for (; i < n4; i += st) {
        float4 v = reinterpret_cast<const float4*>(in)[i];
        f16x4 o = {(f16)v.x, (f16)v.y, (f16)v.z, (f16)v.w};
        reinterpret_cast<f16x4*>(out)[i] = o;
    }
}

// ---------------------------------------------------------------- in_proj GEMM (2-phase core frozen; coalesced epilogue)
// C[8192,3072] = A * B^T + bias; scatter Q (prescaled by 0.125*log2e), K, Vt.
// Epilogue: acc -> LDS tile (As/Bs region, dead after K-loop; [m][n] for Q/K,
// [n][m] for V) with ((row&7)<<4) swizzle -> 16B coalesced global stores.
__global__ __launch_bounds__(256) void gemm_in(const f16* __restrict__ A,
                                               const f16* __restrict__ Bm,
                                               const float* __restrict__ bias,
                                               f16* __restrict__ Qw, f16* __restrict__ Kw,
                                               f16* __restrict__ Vtw) {
    constexpr int K = 1024, NT = K / 32;
    __shared__ __align__(16) char SMEM[32768];
    f16* As = (f16*)SMEM;             // [2][128*32] = 16KB
    f16* Bs = (f16*)(SMEM + 16384);   // [2][128*32] = 16KB
    const int t = threadIdx.x;
    const int wave = t >> 6, lane = t & 63, lr = lane & 15, lg = lane >> 4;
    const int wr = wave >> 1, wc = wave & 1;
    const int wg = blockIdx.x;
    const int swz = (wg & 7) * 192 + (wg >> 3);  // 1536 % 8 == 0 -> bijective
    const int m0 = (swz / 24) * 128, n0 = (swz % 24) * 128;

    const f16* Ag = A + (m0 + (t >> 2)) * K + (t & 3) * 8;
    const f16* Bg = Bm + (n0 + (t >> 2)) * K + (t & 3) * 8;

    f32x4 acc[4][4] = {};

    auto stage = [&](int buf, int kt) {
        const f16* a = Ag + kt * 32;
        const f16* b = Bg + kt * 32;
        f16* al = As + buf * 4096 + t * 8;
        f16* bl = Bs + buf * 4096 + t * 8;
        gload16(a, al);
        gload16(a + 64 * K, al + 64 * 32);
        gload16(b, bl);
        gload16(b + 64 * K, bl + 64 * 32);
    };

    stage(0, 0);
    __syncthreads();
    int cur = 0;
    for (int kt = 0; kt < NT; ++kt) {
        if (kt + 1 < NT) stage(cur ^ 1, kt + 1);
        const f16* as = As + cur * 4096;
        const f16* bs = Bs + cur * 4096;
        f16x8 af[4], bf[4];
#pragma unroll
        for (int i = 0; i < 4; ++i)
            af[i] = *(const f16x8*)&as[(wr * 64 + i * 16 + lr) * 32 + lg * 8];
#pragma unroll
        for (int i = 0; i < 4; ++i)
            bf[i] = *(const f16x8*)&bs[(wc * 64 + i * 16 + lr) * 32 + lg * 8];
#pragma unroll
        for (int i = 0; i < 4; ++i)
#pragma unroll
            for (int j = 0; j < 4; ++j)
                acc[i][j] = __builtin_amdgcn_mfma_f32_16x16x32_f16(af[i], bf[j], acc[i][j], 0, 0, 0);
        __syncthreads();
        cur ^= 1;
    }
    // all LDS reads done (final __syncthreads above) — SMEM reusable as C-tile.

    const float SCQ = 0.18033688011112042f;  // (1/sqrt(64)) * log2(e)
    const int part = n0 >> 10;               // whole 128-tile is in one of Q/K/V
    char* E = SMEM;                          // 128 rows x 256B = 32KB
#pragma unroll
    for (int nf = 0; nf < 4; ++nf) {
        int nl = wc * 64 + nf * 16 + lr;
        float bv = bias[n0 + nl];
#pragma unroll
        for (int mf = 0; mf < 4; ++mf) {
#pragma unroll
            for (int r = 0; r < 4; ++r) {
                int ml = wr * 64 + mf * 16 + lg * 4 + r;
                float x = acc[mf][nf][r] + bv;
                if (part == 0) x *= SCQ;
                f16 hv = (f16)x;
                if (part < 2)  // Q/K: E[m][n]
                    *(f16*)(E + ml * 256 + ((2 * nl) ^ ((ml & 7) << 4))) = hv;
                else           // V: E[n][m] (transposed -> contiguous-in-s stores)
                    *(f16*)(E + nl * 256 + ((2 * ml) ^ ((nl & 7) << 4))) = hv;
            }
        }
    }
    __syncthreads();
    const int chunk = t & 15, co = chunk * 16, rhi = t >> 4;
#pragma unroll
    for (int i = 0; i < 8; ++i) {
        int row = i * 16 + rhi;
        f16x8 v = *(const f16x8*)(E + row * 256 + (co ^ ((row & 7) << 4)));
        if (part < 2) {
            int m = m0 + row, n = n0 + chunk * 8;
            int bb = m >> 10, ss = m & 1023, hh = (n >> 6) & 15, dd = n & 63;
            f16* dst = (part == 0 ? Qw : Kw) + ((bb * 16 + hh) * 1024 + ss) * 64 + dd;
            *(f16x8*)dst = v;
        } else {
            int n = n0 + row, m = m0 + chunk * 8;
            int bb = m >> 10, ss = m & 1023, hh = (n >> 6) & 15, dd = n & 63;
            *(f16x8*)(Vtw + ((bb * 16 + hh) * 64 + dd) * 1024 + ss) = v;
        }
    }
}

// ---------------------------------------------------------------- out_proj GEMM (frozen)
__global__ __launch_bounds__(256) void gemm_out(const f16* __restrict__ A,
                                                const f16* __restrict__ Bm,
                                                const float* __restrict__ bias,
                                                float* __restrict__ Cout) {
    constexpr int K = 1024, NT = K / 32;
    __shared__ f16 As[2][128 * 32];
    __shared__ f16 Bs[2][128 * 32];
    const int t = threadIdx.x;
    const int wave = t >> 6, lane = t & 63, lr = lane & 15, lg = lane >> 4;
    const int wr = wave >> 1, wc = wave & 1;
    const int wg = blockIdx.x;
    const int swz = (wg & 7) * 64 + (wg >> 3);  // 512 % 8 == 0 -> bijective
    const int m0 = (swz / 8) * 128, n0 = (swz % 8) * 128;

    const f16* Ag = A + (m0 + (t >> 2)) * K + (t & 3) * 8;
    const f16* Bg = Bm + (n0 + (t >> 2)) * K + (t & 3) * 8;

    f32x4 acc[4][4] = {};

    auto stage = [&](int buf, int kt) {
        const f16* a = Ag + kt * 32;
        const f16* b = Bg + kt * 32;
        f16* al = &As[buf][t * 8];
        f16* bl = &Bs[buf][t * 8];
        gload16(a, al);
        gload16(a + 64 * K, al + 64 * 32);
        gload16(b, bl);
        gload16(b + 64 * K, bl + 64 * 32);
    };

    stage(0, 0);
    __syncthreads();
    int cur = 0;
    for (int kt = 0; kt < NT; ++kt) {
        if (kt + 1 < NT) stage(cur ^ 1, kt + 1);
        const f16* as = &As[cur][0];
        const f16* bs = &Bs[cur][0];
        f16x8 af[4], bf[4];
#pragma unroll
        for (int i = 0; i < 4; ++i)
            af[i] = *(const f16x8*)&as[(wr * 64 + i * 16 + lr) * 32 + lg * 8];
#pragma unroll
        for (int i = 0; i < 4; ++i)
            bf[i] = *(const f16x8*)&bs[(wc * 64 + i * 16 + lr) * 32 + lg * 8];
#pragma unroll
        for (int i = 0; i < 4; ++i)
#pragma unroll
            for (int j = 0; j < 4; ++j)
                acc[i][j] = __builtin_amdgcn_mfma_f32_16x16x32_f16(af[i], bf[j], acc[i][j], 0, 0, 0);
        __syncthreads();
        cur ^= 1;
    }
#pragma unroll
    for (int nf = 0; nf < 4; ++nf) {
        int n = n0 + wc * 64 + nf * 16 + lr;
        float bv = bias[n];
#pragma unroll
        for (int mf = 0; mf < 4; ++mf) {
            int m = m0 + wr * 64 + mf * 16 + lg * 4;
#pragma unroll
            for (int r = 0; r < 4; ++r) Cout[(m + r) * 1024 + n] = acc[mf][nf][r] + bv;
        }
    }
}

// ---------------------------------------------------------------- flash attention (frozen from round 7)
__global__ __launch_bounds__(256) void attn_kernel(const f16* __restrict__ Qw,
                                                   const f16* __restrict__ Kw,
                                                   const f16* __restrict__ Vtw,
                                                   f16* __restrict__ AO) {
    __shared__ char LDSb[65536];  // K slots: [0,32768) 4x8KB ; V slots: [32768,65536)
    const int t = threadIdx.x, wave = t >> 6, lane = t & 63;
    const int ql = lane & 31, hi = lane >> 5;
    const int wg = blockIdx.x;
    const int gid = (wg & 7) * 128 + (wg >> 3);
    const int qt = gid & 7, h = (gid >> 3) & 15, b = gid >> 7;
    const f16* Qp = Qw + (b * 16 + h) * 1024 * 64;
    const f16* Kp = Kw + (b * 16 + h) * 1024 * 64;
    const f16* Vp = Vtw + (b * 16 + h) * 64 * 1024;
    const int q0 = qt * 128 + wave * 32;

    // Q as B-operand (prescaled): qb[s] = Q[q0+ql][s*16 + hi*8 + j]
    f16x8 qb[4];
#pragma unroll
    for (int s = 0; s < 4; ++s)
        qb[s] = *(const f16x8*)&Qp[(q0 + ql) * 64 + s * 16 + hi * 8];

    // staging: 256 thr x 2 rows each for K and V tiles (64 rows x 128B = 8KB each)
    const int srow0 = t >> 3;
    const int sw = (t & 7) << 4;
    auto stage_kv = [&](int slot, int kv) {  // kv = tile*64
#pragma unroll
        for (int c = 0; c < 2; ++c) {
            int row = c * 32 + srow0;
            int gwb = sw ^ ((row & 7) << 4);  // pre-swizzle SOURCE (rule 21)
            gload16((const char*)(Kp + (kv + row) * 64) + gwb,
                    LDSb + slot * 8192 + c * 4096 + t * 16);
            gload16((const char*)(Vp + row * 1024 + kv) + gwb,
                    LDSb + 32768 + slot * 8192 + c * 4096 + t * 16);
        }
    };

    f32x16 o0 = 0.f, o1 = 0.f;
    float mraw = -1e30f, lsum = 0.f;

    stage_kv(0, 0);
    stage_kv(1, 64);
    stage_kv(2, 128);
    VMCNT(8);  // own slice of slot 0 landed (12 issued, oldest 4 done)

    for (int kv = 0; kv < 16; ++kv) {
        __builtin_amdgcn_s_barrier();
        SCHEDBAR();  // pin: no stage-load may be scheduled above the barrier
        if (kv + 3 < 16) stage_kv((kv + 3) & 3, (kv + 3) * 64);
        const char* Kb = LDSb + (kv & 3) * 8192;
        const char* Vb = LDSb + 32768 + (kv & 3) * 8192;

        // ---- QK^T (swapped): st0 = S^T[kk 0..31][q], st1 = S^T[kk 32..63][q]
        f32x16 st0, st1;
        __builtin_amdgcn_s_setprio(1);
#pragma unroll
        for (int s = 0; s < 4; ++s) {
            int byt = (s * 32 + hi * 16) ^ ((ql & 7) << 4);
            f16x8 k0 = *(const f16x8*)(Kb + ql * 128 + byt);
            f16x8 k1 = *(const f16x8*)(Kb + (32 + ql) * 128 + byt);
            if (s == 0) {
                st0 = __builtin_amdgcn_mfma_f32_32x32x16_f16(k0, qb[0], (f32x16)0.f, 0, 0, 0);
                st1 = __builtin_amdgcn_mfma_f32_32x32x16_f16(k1, qb[0], (f32x16)0.f, 0, 0, 0);
            } else {
                st0 = __builtin_amdgcn_mfma_f32_32x32x16_f16(k0, qb[s], st0, 0, 0, 0);
                st1 = __builtin_amdgcn_mfma_f32_32x32x16_f16(k1, qb[s], st1, 0, 0, 0);
            }
        }
        __builtin_amdgcn_s_setprio(0);

        // ---- lane-local online softmax, tree reductions, defer-max (THR=8 log2)
        float a[16];
#pragma unroll
        for (int r = 0; r < 16; ++r) a[r] = fmaxf(st0[r], st1[r]);
#pragma unroll
        for (int s = 8; s >= 1; s >>= 1)
#pragma unroll
            for (int r = 0; r < 16; ++r)
                if (r < s) a[r] = fmaxf(a[r], a[r + s]);
        float mx = fmaxf(a[0], __shfl_xor(a[0], 32, 64));

        if (__all(mx <= mraw + 8.f)) {
#pragma unroll
            for (int r = 0; r < 16; ++r) st0[r] = exp2f(st0[r] - mraw);
#pragma unroll
            for (int r = 0; r < 16; ++r) st1[r] = exp2f(st1[r] - mraw);
            float sa[16];
#pragma unroll
            for (int r = 0; r < 16; ++r) sa[r] = st0[r] + st1[r];
#pragma unroll
            for (int s = 8; s >= 1; s >>= 1)
#pragma unroll
                for (int r = 0; r < 16; ++r)
                    if (r < s) sa[r] += sa[r + s];
            lsum += sa[0] + __shfl_xor(sa[0], 32, 64);
        } else {
            float mn = fmaxf(mraw, mx);
            float al = exp2f(mraw - mn);
            mraw = mn;
#pragma unroll
            for (int r = 0; r < 16; ++r) st0[r] = exp2f(st0[r] - mn);
#pragma unroll
            for (int r = 0; r < 16; ++r) st1[r] = exp2f(st1[r] - mn);
            float sa[16];
#pragma unroll
            for (int r = 0; r < 16; ++r) sa[r] = st0[r] + st1[r];
#pragma unroll
            for (int s = 8; s >= 1; s >>= 1)
#pragma unroll
                for (int r = 0; r < 16; ++r)
                    if (r < s) sa[r] += sa[r + s];
            lsum = lsum * al + sa[0] + __shfl_xor(sa[0], 32, 64);
            o0 *= al;
            o1 *= al;
        }

        // ---- PV (swapped): O^T[d][q] += V^T[d][kk] P^T[kk][q]
#pragma unroll
        for (int s = 0; s < 4; ++s) {
            const int s1 = s & 1;
            float p0, p1, p2, p3, p4, p5, p6, p7;
            if (s < 2) {
                p0 = st0[8 * s1 + 0]; p1 = st0[8 * s1 + 1]; p2 = st0[8 * s1 + 2]; p3 = st0[8 * s1 + 3];
                p4 = st0[8 * s1 + 4]; p5 = st0[8 * s1 + 5]; p6 = st0[8 * s1 + 6]; p7 = st0[8 * s1 + 7];
            } else {
                p0 = st1[8 * s1 + 0]; p1 = st1[8 * s1 + 1]; p2 = st1[8 * s1 + 2]; p3 = st1[8 * s1 + 3];
                p4 = st1[8 * s1 + 4]; p5 = st1[8 * s1 + 5]; p6 = st1[8 * s1 + 6]; p7 = st1[8 * s1 + 7];
            }
            unsigned c0 = pk2(p0, p1), c1 = pk2(p2, p3);
            unsigned c2 = pk2(p4, p5), c3 = pk2(p6, p7);
            unsigned y0 = __shfl_xor(hi ? c0 : c2, 32, 64);
            unsigned y1 = __shfl_xor(hi ? c1 : c3, 32, 64);
            unsigned w0 = hi ? y0 : c0;
            unsigned w1 = hi ? y1 : c1;
            unsigned w2 = hi ? c2 : y0;
            unsigned w3 = hi ? c3 : y1;
            u32x4 pw = {w0, w1, w2, w3};
            f16x8 pf = __builtin_bit_cast(f16x8, pw);
            __builtin_amdgcn_s_setprio(1);
#pragma unroll
            for (int db = 0; db < 2; ++db) {
                int row = db * 32 + ql;
                int byt = (s * 32 + hi * 16) ^ ((row & 7) << 4);
                f16x8 vf = *(const f16x8*)(Vb + row * 128 + byt);
                if (db == 0)
                    o0 = __builtin_amdgcn_mfma_f32_32x32x16_f16(vf, pf, o0, 0, 0, 0);
                else
                    o1 = __builtin_amdgcn_mfma_f32_32x32x16_f16(vf, pf, o1, 0, 0, 0);
            }
            __builtin_amdgcn_s_setprio(0);
        }
        // pre-barrier wait: own slice of kv+1 landed (counted; never drains mid-loop)
        if (kv <= 12) VMCNT(8);
        else if (kv == 13) VMCNT(4);
        else if (kv == 14) VMCNT(0);
        SCHEDBAR();
    }

    // ---- epilogue: O^T -> LDS (swizzled transpose) -> coalesced AO[s][h*64+d]
    // writes K slots 0-1 ([0,16384)); final iteration read slot 3 — disjoint,
    // and slot 1's last reader (kv=13) is two barriers upstream.
    SCHEDBAR();  // pin: no epilogue store above the final loop barrier
    float inv = 1.0f / lsum;
    char* obase = LDSb + wave * 4096;  // 4 waves x 4KB in dead K region
#pragma unroll
    for (int db = 0; db < 2; ++db)
#pragma unroll
        for (int r = 0; r < 16; ++r) {
            int d = db * 32 + (r & 3) + 8 * (r >> 2) + 4 * hi;
            float v = (db == 0 ? o0[r] : o1[r]) * inv;
            *(f16*)(obase + ql * 128 + ((2 * d) ^ ((ql & 7) << 4))) = (f16)v;
        }
    __syncthreads();
    const int rl = lane >> 1, c4 = (lane & 1) * 4;
#pragma unroll
    for (int i = 0; i < 4; ++i) {
        f16x8 ov = *(const f16x8*)(obase + rl * 128 + (((c4 + i) * 16) ^ ((rl & 7) << 4)));
        *(f16x8*)&AO[(b * 1024 + q0 + rl) * 1024 + h * 64 + (c4 + i) * 8] = ov;
    }
}

// ---------------------------------------------------------------- launch
extern "C" void kernel_launch(void* const* d_in, const int* in_sizes, int n_in,
                              void* d_out, int out_size, void* d_ws, size_t ws_size,
                              hipStream_t stream) {
    const float* qkv = (const float*)d_in[0];
    const float* w_in = (const float*)d_in[1];
    const float* b_in = (const float*)d_in[2];
    const float* w_out = (const float*)d_in[3];
    const float* b_out = (const float*)d_in[4];
    float* out = (float*)d_out;

    f16* Xh = (f16*)d_ws;            // 8192*1024
    f16* Wih = Xh + 8388608;         // 3072*1024
    f16* Woh = Wih + 3145728;        // 1024*1024
    f16* Qw = Woh + 1048576;         // [8][16][1024][64]  (prescaled)
    f16* Kw = Qw + 8388608;          // [8][16][1024][64]
    f16* Vtw = Kw + 8388608;         // [8][16][64][1024]
    f16* AO = Xh;

    cvt_kernel<<<2048, 256, 0, stream>>>(qkv, Xh, 8388608 / 4);
    cvt_kernel<<<1024, 256, 0, stream>>>(w_in, Wih, 3145728 / 4);
    cvt_kernel<<<512, 256, 0, stream>>>(w_out, Woh, 1048576 / 4);

    gemm_in<<<1536, 256, 0, stream>>>(Xh, Wih, b_in, Qw, Kw, Vtw);
    attn_kernel<<<1024, 256, 0, stream>>>(Qw, Kw, Vtw, AO);
    gemm_out<<<512, 256, 0, stream>>>(AO, Woh, b_out, out);
}

// Round 10
// 276.932 us; speedup vs baseline: 1.0844x; 1.0713x over previous
//
#include <hip/hip_runtime.h>

typedef _Float16 f16;
typedef _Float16 f16x4 __attribute__((ext_vector_type(4)));
typedef _Float16 f16x8 __attribute__((ext_vector_type(8)));
typedef float f32x4 __attribute__((ext_vector_type(4)));
typedef float f32x16 __attribute__((ext_vector_type(16)));
typedef unsigned u32x4 __attribute__((ext_vector_type(4)));

#define DEVINL __device__ __forceinline__
#define VMCNT(n) asm volatile("s_waitcnt vmcnt(" #n ")" ::: "memory")
#define SCHEDBAR() __builtin_amdgcn_sched_barrier(0)

// async global->LDS, 16B per lane. LDS dest must be uniform-base + lane*16.
DEVINL void gload16(const void* g, void* l) {
    __builtin_amdgcn_global_load_lds(
        (const __attribute__((address_space(1))) unsigned int*)g,
        (__attribute__((address_space(3))) unsigned int*)l, 16, 0, 0);
}

DEVINL unsigned pk2(float a, float b) {
    auto v = __builtin_amdgcn_cvt_pkrtz(a, b);  // v_cvt_pkrtz_f16_f32
    return __builtin_bit_cast(unsigned, v);
}

// ---------------------------------------------------------------- convert
__global__ __launch_bounds__(256) void cvt_kernel(const float* __restrict__ in,
                                                  f16* __restrict__ out, int n4) {
    int i = blockIdx.x * 256 + threadIdx.x;
    int st = gridDim.x * 256;
    for (; i < n4; i += st) {
        float4 v = reinterpret_cast<const float4*>(in)[i];
        f16x4 o = {(f16)v.x, (f16)v.y, (f16)v.z, (f16)v.w};
        reinterpret_cast<f16x4*>(out)[i] = o;
    }
}

// ---------------------------------------------------------------- in_proj GEMM (frozen from round 9)
__global__ __launch_bounds__(256) void gemm_in(const f16* __restrict__ A,
                                               const f16* __restrict__ Bm,
                                               const float* __restrict__ bias,
                                               f16* __restrict__ Qw, f16* __restrict__ Kw,
                                               f16* __restrict__ Vtw) {
    constexpr int K = 1024, NT = K / 32;
    __shared__ __align__(16) char SMEM[32768];
    f16* As = (f16*)SMEM;             // [2][128*32] = 16KB
    f16* Bs = (f16*)(SMEM + 16384);   // [2][128*32] = 16KB
    const int t = threadIdx.x;
    const int wave = t >> 6, lane = t & 63, lr = lane & 15, lg = lane >> 4;
    const int wr = wave >> 1, wc = wave & 1;
    const int wg = blockIdx.x;
    const int swz = (wg & 7) * 192 + (wg >> 3);  // 1536 % 8 == 0 -> bijective
    const int m0 = (swz / 24) * 128, n0 = (swz % 24) * 128;

    const f16* Ag = A + (m0 + (t >> 2)) * K + (t & 3) * 8;
    const f16* Bg = Bm + (n0 + (t >> 2)) * K + (t & 3) * 8;

    f32x4 acc[4][4] = {};

    auto stage = [&](int buf, int kt) {
        const f16* a = Ag + kt * 32;
        const f16* b = Bg + kt * 32;
        f16* al = As + buf * 4096 + t * 8;
        f16* bl = Bs + buf * 4096 + t * 8;
        gload16(a, al);
        gload16(a + 64 * K, al + 64 * 32);
        gload16(b, bl);
        gload16(b + 64 * K, bl + 64 * 32);
    };

    stage(0, 0);
    __syncthreads();
    int cur = 0;
    for (int kt = 0; kt < NT; ++kt) {
        if (kt + 1 < NT) stage(cur ^ 1, kt + 1);
        const f16* as = As + cur * 4096;
        const f16* bs = Bs + cur * 4096;
        f16x8 af[4], bf[4];
#pragma unroll
        for (int i = 0; i < 4; ++i)
            af[i] = *(const f16x8*)&as[(wr * 64 + i * 16 + lr) * 32 + lg * 8];
#pragma unroll
        for (int i = 0; i < 4; ++i)
            bf[i] = *(const f16x8*)&bs[(wc * 64 + i * 16 + lr) * 32 + lg * 8];
#pragma unroll
        for (int i = 0; i < 4; ++i)
#pragma unroll
            for (int j = 0; j < 4; ++j)
                acc[i][j] = __builtin_amdgcn_mfma_f32_16x16x32_f16(af[i], bf[j], acc[i][j], 0, 0, 0);
        __syncthreads();
        cur ^= 1;
    }
    // all LDS reads done (final __syncthreads above) — SMEM reusable as C-tile.

    const float SCQ = 0.18033688011112042f;  // (1/sqrt(64)) * log2(e)
    const int part = n0 >> 10;               // whole 128-tile is in one of Q/K/V
    char* E = SMEM;                          // 128 rows x 256B = 32KB
#pragma unroll
    for (int nf = 0; nf < 4; ++nf) {
        int nl = wc * 64 + nf * 16 + lr;
        float bv = bias[n0 + nl];
#pragma unroll
        for (int mf = 0; mf < 4; ++mf) {
#pragma unroll
            for (int r = 0; r < 4; ++r) {
                int ml = wr * 64 + mf * 16 + lg * 4 + r;
                float x = acc[mf][nf][r] + bv;
                if (part == 0) x *= SCQ;
                f16 hv = (f16)x;
                if (part < 2)  // Q/K: E[m][n]
                    *(f16*)(E + ml * 256 + ((2 * nl) ^ ((ml & 7) << 4))) = hv;
                else           // V: E[n][m] (transposed -> contiguous-in-s stores)
                    *(f16*)(E + nl * 256 + ((2 * ml) ^ ((nl & 7) << 4))) = hv;
            }
        }
    }
    __syncthreads();
    const int chunk = t & 15, co = chunk * 16, rhi = t >> 4;
#pragma unroll
    for (int i = 0; i < 8; ++i) {
        int row = i * 16 + rhi;
        f16x8 v = *(const f16x8*)(E + row * 256 + (co ^ ((row & 7) << 4)));
        if (part < 2) {
            int m = m0 + row, n = n0 + chunk * 8;
            int bb = m >> 10, ss = m & 1023, hh = (n >> 6) & 15, dd = n & 63;
            f16* dst = (part == 0 ? Qw : Kw) + ((bb * 16 + hh) * 1024 + ss) * 64 + dd;
            *(f16x8*)dst = v;
        } else {
            int n = n0 + row, m = m0 + chunk * 8;
            int bb = m >> 10, ss = m & 1023, hh = (n >> 6) & 15, dd = n & 63;
            *(f16x8*)(Vtw + ((bb * 16 + hh) * 64 + dd) * 1024 + ss) = v;
        }
    }
}

// ---------------------------------------------------------------- out_proj GEMM (frozen)
__global__ __launch_bounds__(256) void gemm_out(const f16* __restrict__ A,
                                                const f16* __restrict__ Bm,
                                                const float* __restrict__ bias,
                                                float* __restrict__ Cout) {
    constexpr int K = 1024, NT = K / 32;
    __shared__ f16 As[2][128 * 32];
    __shared__ f16 Bs[2][128 * 32];
    const int t = threadIdx.x;
    const int wave = t >> 6, lane = t & 63, lr = lane & 15, lg = lane >> 4;
    const int wr = wave >> 1, wc = wave & 1;
    const int wg = blockIdx.x;
    const int swz = (wg & 7) * 64 + (wg >> 3);  // 512 % 8 == 0 -> bijective
    const int m0 = (swz / 8) * 128, n0 = (swz % 8) * 128;

    const f16* Ag = A + (m0 + (t >> 2)) * K + (t & 3) * 8;
    const f16* Bg = Bm + (n0 + (t >> 2)) * K + (t & 3) * 8;

    f32x4 acc[4][4] = {};

    auto stage = [&](int buf, int kt) {
        const f16* a = Ag + kt * 32;
        const f16* b = Bg + kt * 32;
        f16* al = &As[buf][t * 8];
        f16* bl = &Bs[buf][t * 8];
        gload16(a, al);
        gload16(a + 64 * K, al + 64 * 32);
        gload16(b, bl);
        gload16(b + 64 * K, bl + 64 * 32);
    };

    stage(0, 0);
    __syncthreads();
    int cur = 0;
    for (int kt = 0; kt < NT; ++kt) {
        if (kt + 1 < NT) stage(cur ^ 1, kt + 1);
        const f16* as = &As[cur][0];
        const f16* bs = &Bs[cur][0];
        f16x8 af[4], bf[4];
#pragma unroll
        for (int i = 0; i < 4; ++i)
            af[i] = *(const f16x8*)&as[(wr * 64 + i * 16 + lr) * 32 + lg * 8];
#pragma unroll
        for (int i = 0; i < 4; ++i)
            bf[i] = *(const f16x8*)&bs[(wc * 64 + i * 16 + lr) * 32 + lg * 8];
#pragma unroll
        for (int i = 0; i < 4; ++i)
#pragma unroll
            for (int j = 0; j < 4; ++j)
                acc[i][j] = __builtin_amdgcn_mfma_f32_16x16x32_f16(af[i], bf[j], acc[i][j], 0, 0, 0);
        __syncthreads();
        cur ^= 1;
    }
#pragma unroll
    for (int nf = 0; nf < 4; ++nf) {
        int n = n0 + wc * 64 + nf * 16 + lr;
        float bv = bias[n];
#pragma unroll
        for (int mf = 0; mf < 4; ++mf) {
            int m = m0 + wr * 64 + mf * 16 + lg * 4;
#pragma unroll
            for (int r = 0; r < 4; ++r) Cout[(m + r) * 1024 + n] = acc[mf][nf][r] + bv;
        }
    }
}

// ---------------------------------------------------------------- flash attention (4 waves, RING-3, XCD=batch)
// 1024 WGs x 256 thr = 4 waves x 32 q-rows. Ring-3 K/V slots (48 KB LDS total)
// -> 3 blocks/CU (was 2 at 64 KB): raises occupancy 19.7% -> ~30% to feed the
// VALU-bound softmax. Counted vmcnt for prefetch-depth-2 (4 loads/stage):
// steady VMCNT(4), VMCNT(0) only at kv=14. Epilogue scratch = K slots 1-2
// (disjoint from kv=15's slot 0; slot 1's last reader kv=13 is 2 barriers up).
// XCD-chunk: each XCD owns one batch b (4MB K/V = its L2). Q prescaled.
__global__ __launch_bounds__(256) void attn_kernel(const f16* __restrict__ Qw,
                                                   const f16* __restrict__ Kw,
                                                   const f16* __restrict__ Vtw,
                                                   f16* __restrict__ AO) {
    __shared__ char LDSb[49152];  // K slots: [0,24576) 3x8KB ; V slots: [24576,49152) 3x8KB
    const int t = threadIdx.x, wave = t >> 6, lane = t & 63;
    const int ql = lane & 31, hi = lane >> 5;
    const int wg = blockIdx.x;
    const int gid = (wg & 7) * 128 + (wg >> 3);
    const int qt = gid & 7, h = (gid >> 3) & 15, b = gid >> 7;
    const f16* Qp = Qw + (b * 16 + h) * 1024 * 64;
    const f16* Kp = Kw + (b * 16 + h) * 1024 * 64;
    const f16* Vp = Vtw + (b * 16 + h) * 64 * 1024;
    const int q0 = qt * 128 + wave * 32;

    // Q as B-operand (prescaled): qb[s] = Q[q0+ql][s*16 + hi*8 + j]
    f16x8 qb[4];
#pragma unroll
    for (int s = 0; s < 4; ++s)
        qb[s] = *(const f16x8*)&Qp[(q0 + ql) * 64 + s * 16 + hi * 8];

    // staging: 256 thr x 2 rows each for K and V tiles (64 rows x 128B = 8KB each)
    const int srow0 = t >> 3;
    const int sw = (t & 7) << 4;
    auto stage_kv = [&](int slot, int kv) {  // kv = tile*64 ; 4 gload16 per call
#pragma unroll
        for (int c = 0; c < 2; ++c) {
            int row = c * 32 + srow0;
            int gwb = sw ^ ((row & 7) << 4);  // pre-swizzle SOURCE (rule 21)
            gload16((const char*)(Kp + (kv + row) * 64) + gwb,
                    LDSb + slot * 8192 + c * 4096 + t * 16);
            gload16((const char*)(Vp + row * 1024 + kv) + gwb,
                    LDSb + 24576 + slot * 8192 + c * 4096 + t * 16);
        }
    };

    f32x16 o0 = 0.f, o1 = 0.f;
    float mraw = -1e30f, lsum = 0.f;

    stage_kv(0, 0);
    stage_kv(1, 64);
    VMCNT(4);  // slot 0's 4 loads landed (8 issued, oldest 4 done)

    int cs = 0, ps = 2;  // compute slot, prefetch slot (kv+2)%3
    for (int kv = 0; kv < 16; ++kv) {
        __builtin_amdgcn_s_barrier();
        SCHEDBAR();  // pin: no stage-load may be scheduled above the barrier
        if (kv + 2 < 16) stage_kv(ps, (kv + 2) * 64);
        const char* Kb = LDSb + cs * 8192;
        const char* Vb = LDSb + 24576 + cs * 8192;

        // ---- QK^T (swapped): st0 = S^T[kk 0..31][q], st1 = S^T[kk 32..63][q]
        f32x16 st0, st1;
        __builtin_amdgcn_s_setprio(1);
#pragma unroll
        for (int s = 0; s < 4; ++s) {
            int byt = (s * 32 + hi * 16) ^ ((ql & 7) << 4);
            f16x8 k0 = *(const f16x8*)(Kb + ql * 128 + byt);
            f16x8 k1 = *(const f16x8*)(Kb + (32 + ql) * 128 + byt);
            if (s == 0) {
                st0 = __builtin_amdgcn_mfma_f32_32x32x16_f16(k0, qb[0], (f32x16)0.f, 0, 0, 0);
                st1 = __builtin_amdgcn_mfma_f32_32x32x16_f16(k1, qb[0], (f32x16)0.f, 0, 0, 0);
            } else {
                st0 = __builtin_amdgcn_mfma_f32_32x32x16_f16(k0, qb[s], st0, 0, 0, 0);
                st1 = __builtin_amdgcn_mfma_f32_32x32x16_f16(k1, qb[s], st1, 0, 0, 0);
            }
        }
        __builtin_amdgcn_s_setprio(0);

        // ---- lane-local online softmax, tree reductions, defer-max (THR=8 log2)
        float a[16];
#pragma unroll
        for (int r = 0; r < 16; ++r) a[r] = fmaxf(st0[r], st1[r]);
#pragma unroll
        for (int s = 8; s >= 1; s >>= 1)
#pragma unroll
            for (int r = 0; r < 16; ++r)
                if (r < s) a[r] = fmaxf(a[r], a[r + s]);
        float mx = fmaxf(a[0], __shfl_xor(a[0], 32, 64));

        if (__all(mx <= mraw + 8.f)) {
#pragma unroll
            for (int r = 0; r < 16; ++r) st0[r] = exp2f(st0[r] - mraw);
#pragma unroll
            for (int r = 0; r < 16; ++r) st1[r] = exp2f(st1[r] - mraw);
            float sa[16];
#pragma unroll
            for (int r = 0; r < 16; ++r) sa[r] = st0[r] + st1[r];
#pragma unroll
            for (int s = 8; s >= 1; s >>= 1)
#pragma unroll
                for (int r = 0; r < 16; ++r)
                    if (r < s) sa[r] += sa[r + s];
            lsum += sa[0] + __shfl_xor(sa[0], 32, 64);
        } else {
            float mn = fmaxf(mraw, mx);
            float al = exp2f(mraw - mn);
            mraw = mn;
#pragma unroll
            for (int r = 0; r < 16; ++r) st0[r] = exp2f(st0[r] - mn);
#pragma unroll
            for (int r = 0; r < 16; ++r) st1[r] = exp2f(st1[r] - mn);
            float sa[16];
#pragma unroll
            for (int r = 0; r < 16; ++r) sa[r] = st0[r] + st1[r];
#pragma unroll
            for (int s = 8; s >= 1; s >>= 1)
#pragma unroll
                for (int r = 0; r < 16; ++r)
                    if (r < s) sa[r] += sa[r + s];
            lsum = lsum * al + sa[0] + __shfl_xor(sa[0], 32, 64);
            o0 *= al;
            o1 *= al;
        }

        // ---- PV (swapped): O^T[d][q] += V^T[d][kk] P^T[kk][q]
#pragma unroll
        for (int s = 0; s < 4; ++s) {
            const int s1 = s & 1;
            float p0, p1, p2, p3, p4, p5, p6, p7;
            if (s < 2) {
                p0 = st0[8 * s1 + 0]; p1 = st0[8 * s1 + 1]; p2 = st0[8 * s1 + 2]; p3 = st0[8 * s1 + 3];
                p4 = st0[8 * s1 + 4]; p5 = st0[8 * s1 + 5]; p6 = st0[8 * s1 + 6]; p7 = st0[8 * s1 + 7];
            } else {
                p0 = st1[8 * s1 + 0]; p1 = st1[8 * s1 + 1]; p2 = st1[8 * s1 + 2]; p3 = st1[8 * s1 + 3];
                p4 = st1[8 * s1 + 4]; p5 = st1[8 * s1 + 5]; p6 = st1[8 * s1 + 6]; p7 = st1[8 * s1 + 7];
            }
            unsigned c0 = pk2(p0, p1), c1 = pk2(p2, p3);
            unsigned c2 = pk2(p4, p5), c3 = pk2(p6, p7);
            unsigned y0 = __shfl_xor(hi ? c0 : c2, 32, 64);
            unsigned y1 = __shfl_xor(hi ? c1 : c3, 32, 64);
            unsigned w0 = hi ? y0 : c0;
            unsigned w1 = hi ? y1 : c1;
            unsigned w2 = hi ? c2 : y0;
            unsigned w3 = hi ? c3 : y1;
            u32x4 pw = {w0, w1, w2, w3};
            f16x8 pf = __builtin_bit_cast(f16x8, pw);
            __builtin_amdgcn_s_setprio(1);
#pragma unroll
            for (int db = 0; db < 2; ++db) {
                int row = db * 32 + ql;
                int byt = (s * 32 + hi * 16) ^ ((row & 7) << 4);
                f16x8 vf = *(const f16x8*)(Vb + row * 128 + byt);
                if (db == 0)
                    o0 = __builtin_amdgcn_mfma_f32_32x32x16_f16(vf, pf, o0, 0, 0, 0);
                else
                    o1 = __builtin_amdgcn_mfma_f32_32x32x16_f16(vf, pf, o1, 0, 0, 0);
            }
            __builtin_amdgcn_s_setprio(0);
        }
        // pre-barrier wait: next compute slot landed (counted; never drains mid-loop)
        if (kv <= 13) VMCNT(4);
        else if (kv == 14) VMCNT(0);
        SCHEDBAR();
        cs = (cs == 2) ? 0 : cs + 1;
        ps = (ps == 2) ? 0 : ps + 1;
    }

    // ---- epilogue: O^T -> LDS (swizzled transpose) -> coalesced AO[s][h*64+d]
    // scratch = K slots 1-2 ([8192,24576)): disjoint from kv=15's compute slot 0
    // (K and V); slot 1's last reader (kv=13) is two barriers upstream.
    SCHEDBAR();  // pin: no epilogue store above the final loop barrier
    float inv = 1.0f / lsum;
    char* obase = LDSb + 8192 + wave * 4096;  // 4 waves x 4KB in K slots 1-2
#pragma unroll
    for (int db = 0; db < 2; ++db)
#pragma unroll
        for (int r = 0; r < 16; ++r) {
            int d = db * 32 + (r & 3) + 8 * (r >> 2) + 4 * hi;
            float v = (db == 0 ? o0[r] : o1[r]) * inv;
            *(f16*)(obase + ql * 128 + ((2 * d) ^ ((ql & 7) << 4))) = (f16)v;
        }
    __syncthreads();
    const int rl = lane >> 1, c4 = (lane & 1) * 4;
#pragma unroll
    for (int i = 0; i < 4; ++i) {
        f16x8 ov = *(const f16x8*)(obase + rl * 128 + (((c4 + i) * 16) ^ ((rl & 7) << 4)));
        *(f16x8*)&AO[(b * 1024 + q0 + rl) * 1024 + h * 64 + (c4 + i) * 8] = ov;
    }
}

// ---------------------------------------------------------------- launch
extern "C" void kernel_launch(void* const* d_in, const int* in_sizes, int n_in,
                              void* d_out, int out_size, void* d_ws, size_t ws_size,
                              hipStream_t stream) {
    const float* qkv = (const float*)d_in[0];
    const float* w_in = (const float*)d_in[1];
    const float* b_in = (const float*)d_in[2];
    const float* w_out = (const float*)d_in[3];
    const float* b_out = (const float*)d_in[4];
    float* out = (float*)d_out;

    f16* Xh = (f16*)d_ws;            // 8192*1024
    f16* Wih = Xh + 8388608;         // 3072*1024
    f16* Woh = Wih + 3145728;        // 1024*1024
    f16* Qw = Woh + 1048576;         // [8][16][1024][64]  (prescaled)
    f16* Kw = Qw + 8388608;          // [8][16][1024][64]
    f16* Vtw = Kw + 8388608;         // [8][16][64][1024]
    f16* AO = Xh;

    cvt_kernel<<<2048, 256, 0, stream>>>(qkv, Xh, 8388608 / 4);
    cvt_kernel<<<1024, 256, 0, stream>>>(w_in, Wih, 3145728 / 4);
    cvt_kernel<<<512, 256, 0, stream>>>(w_out, Woh, 1048576 / 4);

    gemm_in<<<1536, 256, 0, stream>>>(Xh, Wih, b_in, Qw, Kw, Vtw);
    attn_kernel<<<1024, 256, 0, stream>>>(Qw, Kw, Vtw, AO);
    gemm_out<<<512, 256, 0, stream>>>(AO, Woh, b_out, out);
}